// Round 10
// baseline (175.545 us; speedup 1.0000x reference)
//
#include <hip/hip_runtime.h>

#define F_IN   64
#define HID    32
#define F_OUT  128
#define KPTS   16
#define CAP    80          // bucket capacity; deg~Bin(400k,1/12500), mean 32
// KP_EXTENT = 1.0/1.5 ; 1/KP_EXTENT^2 = 2.25
#define INV_EXT2 2.25f

// --------------------- K1: zero cursor + pos_sub gather + pre-MLP ------------
__global__ __launch_bounds__(256) void k1_pre(
    const float* __restrict__ x, const float* __restrict__ pre_W,
    const float* __restrict__ pre_b, const float* __restrict__ pos,
    const int* __restrict__ idx,
    float* __restrict__ x_side, float* __restrict__ pos_sub,
    int* __restrict__ cursor, int N, int NS)
{
    const int gt = blockIdx.x * 256 + threadIdx.x;
    const int gstride = gridDim.x * 256;

    for (int i = gt; i < NS; i += gstride) cursor[i] = 0;
    for (int i = gt; i < NS * 3; i += gstride) {
        int r = i / 3, c = i - r * 3;
        pos_sub[i] = pos[(long long)idx[r] * 3 + c];
    }

    const int c = threadIdx.x & 31;
    float wcol[F_IN];
#pragma unroll
    for (int a = 0; a < F_IN; ++a) wcol[a] = pre_W[a * HID + c];
    const float bias = pre_b[c];

    const int group   = blockIdx.x * 8 + (threadIdx.x >> 5);
    const int ngroups = gridDim.x * 8;
    for (int row = group; row < N; row += ngroups) {
        const float4* xr = (const float4*)(x + (long long)row * F_IN);
        float acc = bias;
#pragma unroll
        for (int q = 0; q < 16; ++q) {
            const float4 xv = xr[q];
            acc = fmaf(xv.x, wcol[4 * q + 0], acc);
            acc = fmaf(xv.y, wcol[4 * q + 1], acc);
            acc = fmaf(xv.z, wcol[4 * q + 2], acc);
            acc = fmaf(xv.w, wcol[4 * q + 3], acc);
        }
        x_side[(long long)row * HID + c] = acc;
    }
}

// --------------------- K2: per-edge nn/w + bucket scatter --------------------
__global__ __launch_bounds__(256) void k2_prep(
    const float* __restrict__ pos, const float* __restrict__ pos_sub,
    const float* __restrict__ kp,
    const int* __restrict__ edge_src, const int* __restrict__ edge_dst,
    int* __restrict__ cursor, uint2* __restrict__ pkw, int E)
{
    __shared__ float skp[KPTS * 3];
    if (threadIdx.x < KPTS * 3) skp[threadIdx.x] = kp[threadIdx.x];
    __syncthreads();

    for (int t = blockIdx.x * 256 + threadIdx.x; t < E; t += gridDim.x * 256) {
        const int src = edge_src[t];
        const int dst = edge_dst[t];
        const float nx = pos[src * 3 + 0] - pos_sub[dst * 3 + 0];
        const float ny = pos[src * 3 + 1] - pos_sub[dst * 3 + 1];
        const float nz = pos[src * 3 + 2] - pos_sub[dst * 3 + 2];

        float best = 1e30f;
        int   nn   = 0;
#pragma unroll
        for (int k = 0; k < KPTS; ++k) {
            const float dx = nx - skp[k * 3 + 0];
            const float dy = ny - skp[k * 3 + 1];
            const float dz = nz - skp[k * 3 + 2];
            const float sq = dx * dx + dy * dy + dz * dz;
            if (sq < best) { best = sq; nn = k; }   // strict <  == jnp.argmin
        }
        const float w = fmaxf(1.0f - best * INV_EXT2, 0.0f);

        const int slot = atomicAdd(&cursor[dst], 1);
        if (slot < CAP)
            pkw[(long long)dst * CAP + slot] =
                make_uint2((unsigned)src | ((unsigned)nn << 20), __float_as_uint(w));
    }
}

// --------------------- K3: fused S-decomposition aggregation -----------------
// Block = 256 threads = 8 groups; group g owns dst d = blk*8+g.
// Phase A: batched 8 edges/iter, 2-stage pipeline, ALL NAMED SCALARS (no
//          arrays -> nothing demotable to scratch). s[g][nn][l] += w*xs via
//          workgroup-scope ds_add_f32 (bank = lane, conflict-free).
// Phase B: group g holds KW flat rows [g*64,g*64+64) col l (compiler may keep
//          in regs or reload from L1 - both fine); partial dots for all 8 dsts
//          via uniform-broadcast LDS reads; combined via part[] + barrier.
__global__ __launch_bounds__(256, 4) void k3_agg(
    const uint2* __restrict__ pkw, const int* __restrict__ cursor,
    const float* __restrict__ x_side, const float* __restrict__ kw,
    float* __restrict__ agg, int NS, int N)
{
    __shared__ float s_lds[8 * KPTS * HID];   // 16 KB: s[d][ka], ka = k*32+a
    __shared__ float part[8 * 8 * HID];       // 8 KB:  part[d][chunk][c]

    const int l = threadIdx.x & 31;
    const int g = threadIdx.x >> 5;           // 0..7
    const int d = blockIdx.x * 8 + g;

    // cooperative zero of s (4096 floats = 1024 float4)
    float4* s4 = (float4*)s_lds;
#pragma unroll
    for (int i = 0; i < 4; ++i)
        s4[i * 256 + threadIdx.x] = make_float4(0.f, 0.f, 0.f, 0.f);
    __syncthreads();

    float* sg = s_lds + g * (KPTS * HID);

    int cnt = 0;
    if (d < NS) {
        cnt = cursor[d];
        if (cnt > CAP) cnt = CAP;
    }
    const uint2* bp = pkw + (long long)(d < NS ? d : 0) * CAP;

    auto gath = [&](uint2 e) -> float {
        unsigned s = e.x & 0xFFFFFu;
        if (s >= (unsigned)N) s = 0;
        return x_side[s * HID + l];
    };

    // ---------------- phase A: batched, 2-stage pipeline, named scalars ------
    uint2 e0 = bp[0], e1 = bp[1], e2 = bp[2], e3 = bp[3],
          e4 = bp[4], e5 = bp[5], e6 = bp[6], e7 = bp[7];      // blind (padded)
    float x0 = gath(e0), x1 = gath(e1), x2 = gath(e2), x3 = gath(e3),
          x4 = gath(e4), x5 = gath(e5), x6 = gath(e6), x7 = gath(e7);

    for (int i0 = 0; i0 < cnt; i0 += 8) {
        const uint2 f0 = bp[i0 + 8],  f1 = bp[i0 + 9],
                    f2 = bp[i0 + 10], f3 = bp[i0 + 11],
                    f4 = bp[i0 + 12], f5 = bp[i0 + 13],
                    f6 = bp[i0 + 14], f7 = bp[i0 + 15];        // blind (padded)
        const float y0 = gath(f0), y1 = gath(f1), y2 = gath(f2), y3 = gath(f3),
                    y4 = gath(f4), y5 = gath(f5), y6 = gath(f6), y7 = gath(f7);

#define DSADD(J, E, X)                                                         \
        if (i0 + (J) < cnt) {                                                  \
            __hip_atomic_fetch_add(&sg[(int)((E).x >> 20) * HID + l],          \
                                   __uint_as_float((E).y) * (X),               \
                                   __ATOMIC_RELAXED,                           \
                                   __HIP_MEMORY_SCOPE_WORKGROUP);              \
        }
        DSADD(0, e0, x0) DSADD(1, e1, x1) DSADD(2, e2, x2) DSADD(3, e3, x3)
        DSADD(4, e4, x4) DSADD(5, e5, x5) DSADD(6, e6, x6) DSADD(7, e7, x7)
#undef DSADD

        e0 = f0; e1 = f1; e2 = f2; e3 = f3;
        e4 = f4; e5 = f5; e6 = f6; e7 = f7;
        x0 = y0; x1 = y1; x2 = y2; x3 = y3;
        x4 = y4; x5 = y5; x6 = y6; x7 = y7;
    }

    // KW chunk: rows g*64 .. g*64+63, column l (coalesced); in flight over wait
    float kwreg[64];
#pragma unroll
    for (int j = 0; j < 64; ++j)
        kwreg[j] = kw[(g * 64 + j) * HID + l];

    __syncthreads();   // all 8 dsts' s complete

    // ---------------- phase B: registers + uniform LDS broadcasts ------------
    float pacc[8];
#pragma unroll
    for (int dd = 0; dd < 8; ++dd) {
        const float4* srow = (const float4*)(s_lds + dd * (KPTS * HID) + g * 64);
        float acc = 0.f;
#pragma unroll
        for (int q = 0; q < 16; ++q) {
            const float4 sv = srow[q];               // uniform per group: bcast
            acc = fmaf(sv.x, kwreg[4 * q + 0], acc);
            acc = fmaf(sv.y, kwreg[4 * q + 1], acc);
            acc = fmaf(sv.z, kwreg[4 * q + 2], acc);
            acc = fmaf(sv.w, kwreg[4 * q + 3], acc);
        }
        pacc[dd] = acc;
    }

#pragma unroll
    for (int dd = 0; dd < 8; ++dd)
        part[(dd * 8 + g) * HID + l] = pacc[dd];     // bank = l: conflict-free
    __syncthreads();

    // reduce 8 chunks for own dst; lane l = output channel l
    if (d < NS) {
        float r = 0.f;
#pragma unroll
        for (int j = 0; j < 8; ++j)
            r += part[(g * 8 + j) * HID + l];        // bank = l: conflict-free
        agg[(long long)d * HID + l] = r;
    }
}

// --------------------- K4: epilogue, weight columns in registers -------------
__global__ __launch_bounds__(128) void k4_out(
    const float* __restrict__ agg,
    const float* __restrict__ post_W, const float* __restrict__ post_b,
    const float* __restrict__ x,
    const float* __restrict__ short_W, const float* __restrict__ short_b,
    const int* __restrict__ idx, float* __restrict__ out, int NS)
{
    const int c = threadIdx.x;   // 0..127
    float pw[HID];
#pragma unroll
    for (int a = 0; a < HID; ++a) pw[a] = post_W[a * F_OUT + c];
    float sw[F_IN];
#pragma unroll
    for (int b = 0; b < F_IN; ++b) sw[b] = short_W[b * F_OUT + c];
    const float bias = post_b[c] + short_b[c];

    for (int r = blockIdx.x; r < NS; r += gridDim.x) {
        const float4* ar = (const float4*)(agg + (long long)r * HID);
        const float4* xr = (const float4*)(x + (long long)idx[r] * F_IN);
        float acc = bias;
#pragma unroll
        for (int q = 0; q < 8; ++q) {
            const float4 v = ar[q];
            acc = fmaf(v.x, pw[4 * q + 0], acc);
            acc = fmaf(v.y, pw[4 * q + 1], acc);
            acc = fmaf(v.z, pw[4 * q + 2], acc);
            acc = fmaf(v.w, pw[4 * q + 3], acc);
        }
#pragma unroll
        for (int q = 0; q < 16; ++q) {
            const float4 v = xr[q];
            acc = fmaf(v.x, sw[4 * q + 0], acc);
            acc = fmaf(v.y, sw[4 * q + 1], acc);
            acc = fmaf(v.z, sw[4 * q + 2], acc);
            acc = fmaf(v.w, sw[4 * q + 3], acc);
        }
        out[(long long)r * F_OUT + c] = acc;
    }
}

// ---------------------------------------------------------------- launcher
extern "C" void kernel_launch(void* const* d_in, const int* in_sizes, int n_in,
                              void* d_out, int out_size, void* d_ws, size_t ws_size,
                              hipStream_t stream)
{
    const float* x        = (const float*)d_in[0];
    const float* pos      = (const float*)d_in[1];
    const float* pre_W    = (const float*)d_in[2];
    const float* pre_b    = (const float*)d_in[3];
    const float* kp       = (const float*)d_in[4];
    const float* kweight  = (const float*)d_in[5];
    const float* post_W   = (const float*)d_in[6];
    const float* post_b   = (const float*)d_in[7];
    const float* short_W  = (const float*)d_in[8];
    const float* short_b  = (const float*)d_in[9];
    const int*   idx      = (const int*)d_in[10];
    const int*   edge_src = (const int*)d_in[11];
    const int*   edge_dst = (const int*)d_in[12];
    float*       out      = (float*)d_out;

    const int N  = in_sizes[0] / F_IN;
    const int NS = in_sizes[10];
    const int E  = in_sizes[11];

    char* ws = (char*)d_ws;
    size_t off = 0;
    auto alloc = [&](size_t bytes) {
        void* p = ws + off;
        off = (off + bytes + 255) & ~(size_t)255;
        return p;
    };
    float* x_side  = (float*) alloc((size_t)N * HID * 4);
    float* pos_sub = (float*) alloc((size_t)NS * 3 * 4);
    int*   cursor  = (int*)   alloc((size_t)NS * 4);
    uint2* pkw     = (uint2*) alloc(((size_t)NS * CAP + 32) * 8);  // +pad for blind reads
    float* agg     = (float*) alloc((size_t)NS * HID * 4);

    // K1: init + pre-MLP
    k1_pre<<<1536, 256, 0, stream>>>(x, pre_W, pre_b, pos, idx,
                                     x_side, pos_sub, cursor, N, NS);
    // K2: per-edge nn/w + bucket scatter
    k2_prep<<<(E + 255) / 256, 256, 0, stream>>>(pos, pos_sub, kp,
                                                 edge_src, edge_dst,
                                                 cursor, pkw, E);
    // K3: fused aggregation, 8 dsts/block, scalar-batched phase A
    k3_agg<<<(NS + 7) / 8, 256, 0, stream>>>(pkw, cursor, x_side,
                                             kweight, agg, NS, N);
    // K4: epilogue
    k4_out<<<2048, 128, 0, stream>>>(agg, post_W, post_b, x,
                                     short_W, short_b, idx, out, NS);
}

// Round 11
// 167.643 us; speedup vs baseline: 1.0471x; 1.0471x over previous
//
#include <hip/hip_runtime.h>

#define F_IN   64
#define HID    32
#define F_OUT  128
#define KPTS   16
#define CAP    80          // bucket capacity; deg~Bin(400k,1/12500), mean 32
// KP_EXTENT = 1.0/1.5 ; 1/KP_EXTENT^2 = 2.25
#define INV_EXT2 2.25f

// --------------------- K1: zero cursor + pos_sub gather + pre-MLP ------------
__global__ __launch_bounds__(256) void k1_pre(
    const float* __restrict__ x, const float* __restrict__ pre_W,
    const float* __restrict__ pre_b, const float* __restrict__ pos,
    const int* __restrict__ idx,
    float* __restrict__ x_side, float* __restrict__ pos_sub,
    int* __restrict__ cursor, int N, int NS)
{
    const int gt = blockIdx.x * 256 + threadIdx.x;
    const int gstride = gridDim.x * 256;

    for (int i = gt; i < NS; i += gstride) cursor[i] = 0;
    for (int i = gt; i < NS * 3; i += gstride) {
        int r = i / 3, c = i - r * 3;
        pos_sub[i] = pos[(long long)idx[r] * 3 + c];
    }

    const int c = threadIdx.x & 31;
    float wcol[F_IN];
#pragma unroll
    for (int a = 0; a < F_IN; ++a) wcol[a] = pre_W[a * HID + c];
    const float bias = pre_b[c];

    const int group   = blockIdx.x * 8 + (threadIdx.x >> 5);
    const int ngroups = gridDim.x * 8;
    for (int row = group; row < N; row += ngroups) {
        const float4* xr = (const float4*)(x + (long long)row * F_IN);
        float acc = bias;
#pragma unroll
        for (int q = 0; q < 16; ++q) {
            const float4 xv = xr[q];
            acc = fmaf(xv.x, wcol[4 * q + 0], acc);
            acc = fmaf(xv.y, wcol[4 * q + 1], acc);
            acc = fmaf(xv.z, wcol[4 * q + 2], acc);
            acc = fmaf(xv.w, wcol[4 * q + 3], acc);
        }
        x_side[(long long)row * HID + c] = acc;
    }
}

// --------------------- K2: per-edge nn/w + bucket scatter --------------------
__global__ __launch_bounds__(256) void k2_prep(
    const float* __restrict__ pos, const float* __restrict__ pos_sub,
    const float* __restrict__ kp,
    const int* __restrict__ edge_src, const int* __restrict__ edge_dst,
    int* __restrict__ cursor, uint2* __restrict__ pkw, int E)
{
    __shared__ float skp[KPTS * 3];
    if (threadIdx.x < KPTS * 3) skp[threadIdx.x] = kp[threadIdx.x];
    __syncthreads();

    for (int t = blockIdx.x * 256 + threadIdx.x; t < E; t += gridDim.x * 256) {
        const int src = edge_src[t];
        const int dst = edge_dst[t];
        const float nx = pos[src * 3 + 0] - pos_sub[dst * 3 + 0];
        const float ny = pos[src * 3 + 1] - pos_sub[dst * 3 + 1];
        const float nz = pos[src * 3 + 2] - pos_sub[dst * 3 + 2];

        float best = 1e30f;
        int   nn   = 0;
#pragma unroll
        for (int k = 0; k < KPTS; ++k) {
            const float dx = nx - skp[k * 3 + 0];
            const float dy = ny - skp[k * 3 + 1];
            const float dz = nz - skp[k * 3 + 2];
            const float sq = dx * dx + dy * dy + dz * dz;
            if (sq < best) { best = sq; nn = k; }   // strict <  == jnp.argmin
        }
        const float w = fmaxf(1.0f - best * INV_EXT2, 0.0f);

        const int slot = atomicAdd(&cursor[dst], 1);
        if (slot < CAP)
            pkw[(long long)dst * CAP + slot] =
                make_uint2((unsigned)src | ((unsigned)nn << 20), __float_as_uint(w));
    }
}

// --------------------- K3: fused S-decomposition aggregation -----------------
// Block = 256 threads = 8 groups; group g owns dst d = blk*8+g.
// Phase A: batched 8 edges/iter, named scalars only. s accumulate via
//          unsafeAtomicAdd on DIRECTLY-INDEXED __shared__ (addrspace(3)
//          provable -> native ds_add_f32, NOT a flat CAS loop).
// Phase B: group g holds KW flat rows [g*64,g*64+64) col l; partial dots for
//          all 8 dsts via uniform-broadcast LDS reads; combined via part[].
__global__ __launch_bounds__(256, 6) void k3_agg(
    const uint2* __restrict__ pkw, const int* __restrict__ cursor,
    const float* __restrict__ x_side, const float* __restrict__ kw,
    float* __restrict__ agg, int NS, int N)
{
    __shared__ float s_lds[8 * KPTS * HID];   // 16 KB: s[d][ka], ka = k*32+a
    __shared__ float part[8 * 8 * HID];       // 8 KB:  part[d][chunk][c]

    const int l = threadIdx.x & 31;
    const int g = threadIdx.x >> 5;           // 0..7
    const int d = blockIdx.x * 8 + g;
    const int sbase = g * (KPTS * HID) + l;   // this group's column base

    // cooperative zero of s (4096 floats = 1024 float4)
    float4* s4 = (float4*)s_lds;
#pragma unroll
    for (int i = 0; i < 4; ++i)
        s4[i * 256 + threadIdx.x] = make_float4(0.f, 0.f, 0.f, 0.f);
    __syncthreads();

    int cnt = 0;
    if (d < NS) {
        cnt = cursor[d];
        if (cnt > CAP) cnt = CAP;
    }
    const uint2* bp = pkw + (long long)(d < NS ? d : 0) * CAP;

    auto gath = [&](uint2 e) -> float {
        unsigned s = e.x & 0xFFFFFu;
        if (s >= (unsigned)N) s = 0;
        return x_side[s * HID + l];
    };

    // ---------------- phase A: batched, 2-stage pipeline, named scalars ------
    uint2 e0 = bp[0], e1 = bp[1], e2 = bp[2], e3 = bp[3],
          e4 = bp[4], e5 = bp[5], e6 = bp[6], e7 = bp[7];      // blind (padded)
    float x0 = gath(e0), x1 = gath(e1), x2 = gath(e2), x3 = gath(e3),
          x4 = gath(e4), x5 = gath(e5), x6 = gath(e6), x7 = gath(e7);

    for (int i0 = 0; i0 < cnt; i0 += 8) {
        const uint2 f0 = bp[i0 + 8],  f1 = bp[i0 + 9],
                    f2 = bp[i0 + 10], f3 = bp[i0 + 11],
                    f4 = bp[i0 + 12], f5 = bp[i0 + 13],
                    f6 = bp[i0 + 14], f7 = bp[i0 + 15];        // blind (padded)
        const float y0 = gath(f0), y1 = gath(f1), y2 = gath(f2), y3 = gath(f3),
                    y4 = gath(f4), y5 = gath(f5), y6 = gath(f6), y7 = gath(f7);

#define DSADD(J, E, X)                                                         \
        if (i0 + (J) < cnt) {                                                  \
            unsafeAtomicAdd(&s_lds[sbase + (int)((E).x >> 20) * HID],          \
                            __uint_as_float((E).y) * (X));                     \
        }
        DSADD(0, e0, x0) DSADD(1, e1, x1) DSADD(2, e2, x2) DSADD(3, e3, x3)
        DSADD(4, e4, x4) DSADD(5, e5, x5) DSADD(6, e6, x6) DSADD(7, e7, x7)
#undef DSADD

        e0 = f0; e1 = f1; e2 = f2; e3 = f3;
        e4 = f4; e5 = f5; e6 = f6; e7 = f7;
        x0 = y0; x1 = y1; x2 = y2; x3 = y3;
        x4 = y4; x5 = y5; x6 = y6; x7 = y7;
    }

    // KW chunk: rows g*64 .. g*64+63, column l (coalesced); in flight over wait
    float kwreg[64];
#pragma unroll
    for (int j = 0; j < 64; ++j)
        kwreg[j] = kw[(g * 64 + j) * HID + l];

    __syncthreads();   // all 8 dsts' s complete

    // ---------------- phase B: registers + uniform LDS broadcasts ------------
    float pacc[8];
#pragma unroll
    for (int dd = 0; dd < 8; ++dd) {
        const float4* srow = (const float4*)(s_lds + dd * (KPTS * HID) + g * 64);
        float acc = 0.f;
#pragma unroll
        for (int q = 0; q < 16; ++q) {
            const float4 sv = srow[q];               // uniform per group: bcast
            acc = fmaf(sv.x, kwreg[4 * q + 0], acc);
            acc = fmaf(sv.y, kwreg[4 * q + 1], acc);
            acc = fmaf(sv.z, kwreg[4 * q + 2], acc);
            acc = fmaf(sv.w, kwreg[4 * q + 3], acc);
        }
        pacc[dd] = acc;
    }

#pragma unroll
    for (int dd = 0; dd < 8; ++dd)
        part[(dd * 8 + g) * HID + l] = pacc[dd];     // bank = l: conflict-free
    __syncthreads();

    // reduce 8 chunks for own dst; lane l = output channel l
    if (d < NS) {
        float r = 0.f;
#pragma unroll
        for (int j = 0; j < 8; ++j)
            r += part[(g * 8 + j) * HID + l];        // bank = l: conflict-free
        agg[(long long)d * HID + l] = r;
    }
}

// --------------------- K4: epilogue, weight columns in registers -------------
__global__ __launch_bounds__(128) void k4_out(
    const float* __restrict__ agg,
    const float* __restrict__ post_W, const float* __restrict__ post_b,
    const float* __restrict__ x,
    const float* __restrict__ short_W, const float* __restrict__ short_b,
    const int* __restrict__ idx, float* __restrict__ out, int NS)
{
    const int c = threadIdx.x;   // 0..127
    float pw[HID];
#pragma unroll
    for (int a = 0; a < HID; ++a) pw[a] = post_W[a * F_OUT + c];
    float sw[F_IN];
#pragma unroll
    for (int b = 0; b < F_IN; ++b) sw[b] = short_W[b * F_OUT + c];
    const float bias = post_b[c] + short_b[c];

    for (int r = blockIdx.x; r < NS; r += gridDim.x) {
        const float4* ar = (const float4*)(agg + (long long)r * HID);
        const float4* xr = (const float4*)(x + (long long)idx[r] * F_IN);
        float acc = bias;
#pragma unroll
        for (int q = 0; q < 8; ++q) {
            const float4 v = ar[q];
            acc = fmaf(v.x, pw[4 * q + 0], acc);
            acc = fmaf(v.y, pw[4 * q + 1], acc);
            acc = fmaf(v.z, pw[4 * q + 2], acc);
            acc = fmaf(v.w, pw[4 * q + 3], acc);
        }
#pragma unroll
        for (int q = 0; q < 16; ++q) {
            const float4 v = xr[q];
            acc = fmaf(v.x, sw[4 * q + 0], acc);
            acc = fmaf(v.y, sw[4 * q + 1], acc);
            acc = fmaf(v.z, sw[4 * q + 2], acc);
            acc = fmaf(v.w, sw[4 * q + 3], acc);
        }
        out[(long long)r * F_OUT + c] = acc;
    }
}

// ---------------------------------------------------------------- launcher
extern "C" void kernel_launch(void* const* d_in, const int* in_sizes, int n_in,
                              void* d_out, int out_size, void* d_ws, size_t ws_size,
                              hipStream_t stream)
{
    const float* x        = (const float*)d_in[0];
    const float* pos      = (const float*)d_in[1];
    const float* pre_W    = (const float*)d_in[2];
    const float* pre_b    = (const float*)d_in[3];
    const float* kp       = (const float*)d_in[4];
    const float* kweight  = (const float*)d_in[5];
    const float* post_W   = (const float*)d_in[6];
    const float* post_b   = (const float*)d_in[7];
    const float* short_W  = (const float*)d_in[8];
    const float* short_b  = (const float*)d_in[9];
    const int*   idx      = (const int*)d_in[10];
    const int*   edge_src = (const int*)d_in[11];
    const int*   edge_dst = (const int*)d_in[12];
    float*       out      = (float*)d_out;

    const int N  = in_sizes[0] / F_IN;
    const int NS = in_sizes[10];
    const int E  = in_sizes[11];

    char* ws = (char*)d_ws;
    size_t off = 0;
    auto alloc = [&](size_t bytes) {
        void* p = ws + off;
        off = (off + bytes + 255) & ~(size_t)255;
        return p;
    };
    float* x_side  = (float*) alloc((size_t)N * HID * 4);
    float* pos_sub = (float*) alloc((size_t)NS * 3 * 4);
    int*   cursor  = (int*)   alloc((size_t)NS * 4);
    uint2* pkw     = (uint2*) alloc(((size_t)NS * CAP + 32) * 8);  // +pad for blind reads
    float* agg     = (float*) alloc((size_t)NS * HID * 4);

    // K1: init + pre-MLP
    k1_pre<<<1536, 256, 0, stream>>>(x, pre_W, pre_b, pos, idx,
                                     x_side, pos_sub, cursor, N, NS);
    // K2: per-edge nn/w + bucket scatter
    k2_prep<<<(E + 255) / 256, 256, 0, stream>>>(pos, pos_sub, kp,
                                                 edge_src, edge_dst,
                                                 cursor, pkw, E);
    // K3: fused aggregation, 8 dsts/block, native ds_add_f32
    k3_agg<<<(NS + 7) / 8, 256, 0, stream>>>(pkw, cursor, x_side,
                                             kweight, agg, NS, N);
    // K4: epilogue
    k4_out<<<2048, 128, 0, stream>>>(agg, post_W, post_b, x,
                                     short_W, short_b, idx, out, NS);
}